// Round 8
// baseline (917.458 us; speedup 1.0000x reference)
//
#include <hip/hip_runtime.h>
#include <math.h>

#define BB 32
#define TT 128
#define EE 128
#define HD 128
#define G4 512   // 4*H
#define NV 32000

typedef _Float16 f16x2 __attribute__((ext_vector_type(2)));
typedef _Float16 f16x8 __attribute__((ext_vector_type(8)));
typedef float    f32x4 __attribute__((ext_vector_type(4)));

// ---------------- Kernel A (fused): blocks 0..1999 split Wd, 2000..2511 embed ----------------
__global__ __launch_bounds__(256) void k_prep(
    const int* __restrict__ inputs, const float* __restrict__ emb,
    const float* __restrict__ W0, const float* __restrict__ b0,
    float* __restrict__ Z0x,
    const float* __restrict__ Wd, _Float16* __restrict__ Whi, _Float16* __restrict__ Wlo)
{
    if (blockIdx.x < 2000) {
        if (Whi == nullptr) return;   // small-ws fallback: no split buffers
        const int g = blockIdx.x * 256 + threadIdx.x;
        const int chunk = g >> 6;           // 0..7999
        const int lane = g & 63;
        const int ntile = chunk >> 2;
        const int kstep = chunk & 3;
        const int n = ntile * 16 + (lane & 15);
        const int kb = kstep * 32 + (lane >> 4) * 8;
        _Float16 hi[8], lo[8];
        #pragma unroll
        for (int j = 0; j < 8; ++j) {
            float v = Wd[(size_t)(kb + j) * NV + n];
            hi[j] = (_Float16)v;
            lo[j] = (_Float16)(v - (float)hi[j]);
        }
        *(float4*)&Whi[(size_t)chunk * 512 + lane * 8] = *(const float4*)hi;
        *(float4*)&Wlo[(size_t)chunk * 512 + lane * 8] = *(const float4*)lo;
        return;
    }
    __shared__ float xs[8][EE];
    const int r0 = (blockIdx.x - 2000) * 8;
    const int tid = threadIdx.x;
    for (int i = tid; i < 8 * EE; i += 256) {
        int r = i >> 7, e = i & 127;
        int tok = inputs[r0 + r];
        xs[r][e] = emb[tok * EE + e];
    }
    __syncthreads();
    const int c2 = tid * 2;
    float2 bb2 = *(const float2*)&b0[c2];
    float acc[8][2];
    #pragma unroll
    for (int r = 0; r < 8; ++r) { acc[r][0] = bb2.x; acc[r][1] = bb2.y; }
    for (int e = 0; e < EE; ++e) {
        float2 w = *(const float2*)&W0[e * G4 + c2];
        #pragma unroll
        for (int r = 0; r < 8; ++r) {
            float x = xs[r][e];
            acc[r][0] = fmaf(x, w.x, acc[r][0]);
            acc[r][1] = fmaf(x, w.y, acc[r][1]);
        }
    }
    #pragma unroll
    for (int r = 0; r < 8; ++r) {
        float2 o2; o2.x = acc[r][0]; o2.y = acc[r][1];
        *(float2*)&Z0x[(size_t)(r0 + r) * G4 + c2] = o2;
    }
}

// ---------------- Kernel B: 2-layer LSTM, REGISTER-FORCED weights ----------------
// 32 blocks x 256 threads, launch_bounds(256,1) -> 512 VGPR budget (1 wave/SIMD).
// Thread owns gate columns {tid, tid+256}. Weights in 96 NAMED f16x8 vars
// (384 VGPR) — no arrays, so nothing can be demoted to scratch.
#define REPEAT16(X) X(0) X(1) X(2) X(3) X(4) X(5) X(6) X(7) \
                    X(8) X(9) X(10) X(11) X(12) X(13) X(14) X(15)

#define D2(ACC, H, V, J) \
    ACC = __builtin_amdgcn_fdot2(__builtin_shufflevector(H, H, 2*(J), 2*(J)+1), \
                                 __builtin_shufflevector(V, V, 2*(J), 2*(J)+1), ACC, false)
#define DOT8(ACC, H, V) do { D2(ACC,H,V,0); D2(ACC,H,V,1); D2(ACC,H,V,2); D2(ACC,H,V,3); } while (0)

#define LDW(VAR, MAT, COL, I) do { \
    f16x8 _v; \
    _v[0] = (_Float16)MAT[((I)*8 + 0) * G4 + (COL)]; \
    _v[1] = (_Float16)MAT[((I)*8 + 1) * G4 + (COL)]; \
    _v[2] = (_Float16)MAT[((I)*8 + 2) * G4 + (COL)]; \
    _v[3] = (_Float16)MAT[((I)*8 + 3) * G4 + (COL)]; \
    _v[4] = (_Float16)MAT[((I)*8 + 4) * G4 + (COL)]; \
    _v[5] = (_Float16)MAT[((I)*8 + 5) * G4 + (COL)]; \
    _v[6] = (_Float16)MAT[((I)*8 + 6) * G4 + (COL)]; \
    _v[7] = (_Float16)MAT[((I)*8 + 7) * G4 + (COL)]; \
    VAR = _v; } while (0)

#define DECLW(i) f16x8 u0a##i, u0b##i, u1a##i, u1b##i, w1a##i, w1b##i;
#define LOADW(i) \
    LDW(u0a##i, U0, ca, i); LDW(u0b##i, U0, cb, i); \
    LDW(u1a##i, U1, ca, i); LDW(u1b##i, U1, cb, i); \
    LDW(w1a##i, W1, ca, i); LDW(w1b##i, W1, cb, i);
#define PHASEA(i) { f16x8 h0c = h0q[i]; DOT8(z0a, h0c, u0a##i); DOT8(z0b, h0c, u0b##i); \
                    f16x8 h1c = h1q[i]; DOT8(zua, h1c, u1a##i); DOT8(zub, h1c, u1b##i); }
#define PHASEC(i) { f16x8 h0c = h0q[i]; \
                    DOT8((((i)&1) ? z1a2 : z1a1), h0c, w1a##i); \
                    DOT8((((i)&1) ? z1b2 : z1b1), h0c, w1b##i); }

__global__ __launch_bounds__(256, 1) void k_lstm_r2(
    const float* __restrict__ Z0x,
    const float* __restrict__ U0, const float* __restrict__ W1,
    const float* __restrict__ U1, const float* __restrict__ b1,
    float* __restrict__ y)
{
    const int b = blockIdx.x;
    const int tid = threadIdx.x;
    const int ca = tid;          // column A
    const int cb = tid + 256;    // column B

    __shared__ _Float16 h0p[HD];
    __shared__ _Float16 h1p[HD];
    __shared__ float zb[G4];
    __shared__ float zu[G4];

    REPEAT16(DECLW)
    REPEAT16(LOADW)

    const float b1a = b1[ca], b1b = b1[cb];
    const float* __restrict__ zrow = Z0x + (size_t)b * TT * G4;

    float c0 = 0.f, c1 = 0.f;   // cell states (threads 0..127)
    if (tid < HD) { h0p[tid] = (_Float16)0.f; h1p[tid] = (_Float16)0.f; }
    __syncthreads();

    const f16x8* h0q = (const f16x8*)h0p;   // 16 chunks of 8 halves
    const f16x8* h1q = (const f16x8*)h1p;

    for (int t = 0; t < TT; ++t) {
        // ---- phase A: z0 = Z0x[b,t] + h0@U0 (cols a,b); zu = h1@U1 ----
        float z0a = zrow[(size_t)t * G4 + ca];
        float z0b = zrow[(size_t)t * G4 + cb];
        float zua = 0.f, zub = 0.f;
        REPEAT16(PHASEA)
        zb[ca] = z0a; zb[cb] = z0b;
        zu[ca] = zua; zu[cb] = zub;
        __syncthreads();

        // ---- phase B: layer-0 gates -> h0_t ----
        if (tid < HD) {
            float zi = zb[tid], zf = zb[HD + tid], zc = zb[2 * HD + tid], zo = zb[3 * HD + tid];
            float ig = 1.f / (1.f + expf(-zi));
            float fg = 1.f / (1.f + expf(-zf));
            float og = 1.f / (1.f + expf(-zo));
            c0 = fg * c0 + ig * tanhf(zc);
            h0p[tid] = (_Float16)(og * tanhf(c0));
        }
        __syncthreads();

        // ---- phase C: z1 = b1 + zu + h0_t@W1 ----
        float z1a1 = b1a + zu[ca], z1a2 = 0.f;
        float z1b1 = b1b + zu[cb], z1b2 = 0.f;
        REPEAT16(PHASEC)
        zb[ca] = z1a1 + z1a2;
        zb[cb] = z1b1 + z1b2;
        __syncthreads();

        // ---- phase D: layer-1 gates -> h1_t, y ----
        if (tid < HD) {
            float zi = zb[tid], zf = zb[HD + tid], zc = zb[2 * HD + tid], zo = zb[3 * HD + tid];
            float ig = 1.f / (1.f + expf(-zi));
            float fg = 1.f / (1.f + expf(-zf));
            float og = 1.f / (1.f + expf(-zo));
            c1 = fg * c1 + ig * tanhf(zc);
            float hn = og * tanhf(c1);
            h1p[tid] = (_Float16)hn;
            y[(size_t)(b * TT + t) * HD + tid] = hn;
        }
        __syncthreads();
    }
}

// ---------------- Prep: split y into f16 hi/lo, MFMA-fragment-packed ----------------
__global__ __launch_bounds__(256) void k_ysplit(
    const float* __restrict__ y, _Float16* __restrict__ yhi, _Float16* __restrict__ ylo)
{
    const int g = blockIdx.x * 256 + threadIdx.x;
    const int chunk = g >> 6;           // 0..1023
    const int lane = g & 63;
    const int mtile = chunk >> 2;
    const int kstep = chunk & 3;
    const int row = mtile * 16 + (lane & 15);
    const int kb = kstep * 32 + (lane >> 4) * 8;
    _Float16 hi[8], lo[8];
    #pragma unroll
    for (int j = 0; j < 8; ++j) {
        float v = y[(size_t)row * HD + kb + j];
        hi[j] = (_Float16)v;
        lo[j] = (_Float16)(v - (float)hi[j]);
    }
    *(float4*)&yhi[(size_t)chunk * 512 + lane * 8] = *(const float4*)hi;
    *(float4*)&ylo[(size_t)chunk * 512 + lane * 8] = *(const float4*)lo;
}

// ---------------- Kernel C (MFMA): out = y @ Wd + bd via f16 hi/lo split ----------------
__global__ __launch_bounds__(256) void k_dense_mfma(
    const _Float16* __restrict__ yhi, const _Float16* __restrict__ ylo,
    const _Float16* __restrict__ Whi, const _Float16* __restrict__ Wlo,
    const float* __restrict__ bd, float* __restrict__ out)
{
    const int tid = threadIdx.x;
    const int w = tid >> 6;
    const int lane = tid & 63;
    const int mtile = blockIdx.x * 4 + w;
    const int nt0 = blockIdx.y * 20;

    f16x8 Ah[4], Al[4];
    #pragma unroll
    for (int k = 0; k < 4; ++k) {
        Ah[k] = *(const f16x8*)&yhi[(size_t)(mtile * 4 + k) * 512 + lane * 8];
        Al[k] = *(const f16x8*)&ylo[(size_t)(mtile * 4 + k) * 512 + lane * 8];
    }

    const int m0 = mtile * 16;
    const int r0 = (lane >> 4) * 4;          // C/D row group (m89 mapping)

    for (int nt = 0; nt < 20; ++nt) {
        const int ntile = nt0 + nt;
        const size_t cbb = (size_t)ntile * 4 * 512 + lane * 8;
        f16x8 Bh[4], Bl[4];
        #pragma unroll
        for (int k = 0; k < 4; ++k) {
            Bh[k] = *(const f16x8*)&Whi[cbb + k * 512];
            Bl[k] = *(const f16x8*)&Wlo[cbb + k * 512];
        }
        f32x4 acc0 = {0.f, 0.f, 0.f, 0.f};
        f32x4 acc1 = {0.f, 0.f, 0.f, 0.f};
        #pragma unroll
        for (int k = 0; k < 4; ++k) {
            acc0 = __builtin_amdgcn_mfma_f32_16x16x32_f16(Ah[k], Bh[k], acc0, 0, 0, 0);
            acc1 = __builtin_amdgcn_mfma_f32_16x16x32_f16(Ah[k], Bl[k], acc1, 0, 0, 0);
            acc1 = __builtin_amdgcn_mfma_f32_16x16x32_f16(Al[k], Bh[k], acc1, 0, 0, 0);
        }
        const int col = ntile * 16 + (lane & 15);
        const float bias = bd[col];
        #pragma unroll
        for (int reg = 0; reg < 4; ++reg) {
            out[(size_t)(m0 + r0 + reg) * NV + col] = acc0[reg] + acc1[reg] + bias;
        }
    }
}

// ---------------- Kernel C (fallback, fp32 vector) ----------------
__global__ __launch_bounds__(256) void k_dense(
    const float* __restrict__ y, const float* __restrict__ Wd,
    const float* __restrict__ bd, float* __restrict__ out)
{
    __shared__ float ys[64 * HD];
    const int r0 = blockIdx.x * 64;
    const int v0 = blockIdx.y * 128;
    const int tid = threadIdx.x;
    for (int idx = tid; idx < 64 * HD; idx += 256) ys[idx] = y[(size_t)r0 * HD + idx];
    __syncthreads();
    const int tx = tid & 31;
    const int ty = tid >> 5;
    const int v = v0 + tx * 4;
    float4 bd4 = *(const float4*)&bd[v];
    float acc[8][4] = {};
    const float* yrow = &ys[(ty * 8) * HD];
    #pragma unroll 4
    for (int e = 0; e < HD; ++e) {
        float4 wv = *(const float4*)&Wd[(size_t)e * NV + v];
        #pragma unroll
        for (int j = 0; j < 8; ++j) {
            float yv = yrow[j * HD + e];
            acc[j][0] = fmaf(yv, wv.x, acc[j][0]);
            acc[j][1] = fmaf(yv, wv.y, acc[j][1]);
            acc[j][2] = fmaf(yv, wv.z, acc[j][2]);
            acc[j][3] = fmaf(yv, wv.w, acc[j][3]);
        }
    }
    #pragma unroll
    for (int j = 0; j < 8; ++j) {
        int rr = r0 + ty * 8 + j;
        float4 o4;
        o4.x = acc[j][0] + bd4.x;
        o4.y = acc[j][1] + bd4.y;
        o4.z = acc[j][2] + bd4.z;
        o4.w = acc[j][3] + bd4.w;
        *(float4*)&out[(size_t)rr * NV + v] = o4;
    }
}

extern "C" void kernel_launch(void* const* d_in, const int* in_sizes, int n_in,
                              void* d_out, int out_size, void* d_ws, size_t ws_size,
                              hipStream_t stream)
{
    const int*   inputs = (const int*)  d_in[0];
    const float* emb    = (const float*)d_in[1];
    const float* W0     = (const float*)d_in[2];
    const float* U0     = (const float*)d_in[3];
    const float* b0     = (const float*)d_in[4];
    const float* W1     = (const float*)d_in[5];
    const float* U1     = (const float*)d_in[6];
    const float* b1     = (const float*)d_in[7];
    const float* Wd     = (const float*)d_in[8];
    const float* bd     = (const float*)d_in[9];
    float* out = (float*)d_out;

    // ws layout (MFMA path): Z0x 8MB | yy 2MB | Whi 8MB | Wlo 8MB | yhi 1MB | ylo 1MB
    const size_t Z0X_B = (size_t)8 * 1024 * 1024;
    const size_t YY_B  = (size_t)2 * 1024 * 1024;
    const size_t WSP_B = (size_t)8000 * 512 * 2;        // 8,192,000
    const size_t YSP_B = (size_t)1024 * 512 * 2;        // 1,048,576
    const size_t NEED  = Z0X_B + YY_B + 2 * WSP_B + 2 * YSP_B + 4096;

    char* ws = (char*)d_ws;

    if (ws_size >= NEED) {
        float*     Z0x = (float*)ws;
        float*     yy  = (float*)(ws + Z0X_B);
        _Float16*  Whi = (_Float16*)(ws + Z0X_B + YY_B);
        _Float16*  Wlo = (_Float16*)(ws + Z0X_B + YY_B + WSP_B);
        _Float16*  yhi = (_Float16*)(ws + Z0X_B + YY_B + 2 * WSP_B);
        _Float16*  ylo = (_Float16*)(ws + Z0X_B + YY_B + 2 * WSP_B + YSP_B);

        k_prep<<<2512, 256, 0, stream>>>(inputs, emb, W0, b0, Z0x, Wd, Whi, Wlo);
        k_lstm_r2<<<BB, 256, 0, stream>>>(Z0x, U0, W1, U1, b1, yy);
        k_ysplit<<<256, 256, 0, stream>>>(yy, yhi, ylo);
        k_dense_mfma<<<dim3(64, 100), 256, 0, stream>>>(yhi, ylo, Whi, Wlo, bd, out);
    } else {
        // small-ws fallback: Z0x in d_out tail, yy in ws, fp32 dense
        float* yy = (float*)ws;
        size_t out_bytes = (size_t)out_size * sizeof(float);
        float* Z0x = (float*)((char*)d_out + out_bytes - Z0X_B);

        k_prep<<<2512, 256, 0, stream>>>(inputs, emb, W0, b0, Z0x,
                                         Wd, nullptr, nullptr);
        k_lstm_r2<<<BB, 256, 0, stream>>>(Z0x, U0, W1, U1, b1, yy);
        k_dense<<<dim3(64, 250), 256, 0, stream>>>(yy, Wd, bd, out);
    }
}

// Round 9
// 649.327 us; speedup vs baseline: 1.4129x; 1.4129x over previous
//
#include <hip/hip_runtime.h>
#include <math.h>

#define BB 32
#define TT 128
#define EE 128
#define HD 128
#define G4 512   // 4*H
#define NV 32000

typedef _Float16 f16x2 __attribute__((ext_vector_type(2)));
typedef _Float16 f16x8 __attribute__((ext_vector_type(8)));
typedef float    f32x4 __attribute__((ext_vector_type(4)));

// ---------------- Kernel A (fused): blocks 0..1999 split Wd, 2000..2511 embed ----------------
__global__ __launch_bounds__(256) void k_prep(
    const int* __restrict__ inputs, const float* __restrict__ emb,
    const float* __restrict__ W0, const float* __restrict__ b0,
    float* __restrict__ Z0x,
    const float* __restrict__ Wd, _Float16* __restrict__ Whi, _Float16* __restrict__ Wlo)
{
    if (blockIdx.x < 2000) {
        if (Whi == nullptr) return;   // small-ws fallback: no split buffers
        const int g = blockIdx.x * 256 + threadIdx.x;
        const int chunk = g >> 6;           // 0..7999
        const int lane = g & 63;
        const int ntile = chunk >> 2;
        const int kstep = chunk & 3;
        const int n = ntile * 16 + (lane & 15);
        const int kb = kstep * 32 + (lane >> 4) * 8;
        _Float16 hi[8], lo[8];
        #pragma unroll
        for (int j = 0; j < 8; ++j) {
            float v = Wd[(size_t)(kb + j) * NV + n];
            hi[j] = (_Float16)v;
            lo[j] = (_Float16)(v - (float)hi[j]);
        }
        *(float4*)&Whi[(size_t)chunk * 512 + lane * 8] = *(const float4*)hi;
        *(float4*)&Wlo[(size_t)chunk * 512 + lane * 8] = *(const float4*)lo;
        return;
    }
    __shared__ float xs[8][EE];
    const int r0 = (blockIdx.x - 2000) * 8;
    const int tid = threadIdx.x;
    for (int i = tid; i < 8 * EE; i += 256) {
        int r = i >> 7, e = i & 127;
        int tok = inputs[r0 + r];
        xs[r][e] = emb[tok * EE + e];
    }
    __syncthreads();
    const int c2 = tid * 2;
    float2 bb2 = *(const float2*)&b0[c2];
    float acc[8][2];
    #pragma unroll
    for (int r = 0; r < 8; ++r) { acc[r][0] = bb2.x; acc[r][1] = bb2.y; }
    for (int e = 0; e < EE; ++e) {
        float2 w = *(const float2*)&W0[e * G4 + c2];
        #pragma unroll
        for (int r = 0; r < 8; ++r) {
            float x = xs[r][e];
            acc[r][0] = fmaf(x, w.x, acc[r][0]);
            acc[r][1] = fmaf(x, w.y, acc[r][1]);
        }
    }
    #pragma unroll
    for (int r = 0; r < 8; ++r) {
        float2 o2; o2.x = acc[r][0]; o2.y = acc[r][1];
        *(float2*)&Z0x[(size_t)(r0 + r) * G4 + c2] = o2;
    }
}

// ---------------- Kernel B: 2-layer LSTM, register-resident weights ----------------
// 32 blocks x 512 threads, launch_bounds(512,2) -> 256 VGPR/wave cap (HW max),
// 2 waves/SIMD. Thread owns ONE gate column (tid) of each matrix: 48 NAMED
// f16x8 vars = 192 weight VGPRs + ~35 working < 256. Named vars (not arrays)
// so SROA can't demote to scratch (round-5 failure), and demand is under the
// 256 architected cap (round-8 failure).
#define REPEAT16(X) X(0) X(1) X(2) X(3) X(4) X(5) X(6) X(7) \
                    X(8) X(9) X(10) X(11) X(12) X(13) X(14) X(15)

#define D2(ACC, H, V, J) \
    ACC = __builtin_amdgcn_fdot2(__builtin_shufflevector(H, H, 2*(J), 2*(J)+1), \
                                 __builtin_shufflevector(V, V, 2*(J), 2*(J)+1), ACC, false)
#define DOT8(ACC, H, V) do { D2(ACC,H,V,0); D2(ACC,H,V,1); D2(ACC,H,V,2); D2(ACC,H,V,3); } while (0)

#define LDW(VAR, MAT, COL, I) do { \
    f16x8 _v; \
    _v[0] = (_Float16)MAT[((I)*8 + 0) * G4 + (COL)]; \
    _v[1] = (_Float16)MAT[((I)*8 + 1) * G4 + (COL)]; \
    _v[2] = (_Float16)MAT[((I)*8 + 2) * G4 + (COL)]; \
    _v[3] = (_Float16)MAT[((I)*8 + 3) * G4 + (COL)]; \
    _v[4] = (_Float16)MAT[((I)*8 + 4) * G4 + (COL)]; \
    _v[5] = (_Float16)MAT[((I)*8 + 5) * G4 + (COL)]; \
    _v[6] = (_Float16)MAT[((I)*8 + 6) * G4 + (COL)]; \
    _v[7] = (_Float16)MAT[((I)*8 + 7) * G4 + (COL)]; \
    VAR = _v; } while (0)

#define DECLW(i) f16x8 u0_##i, u1_##i, w1_##i;
#define LOADW(i) LDW(u0_##i, U0, tid, i); LDW(u1_##i, U1, tid, i); LDW(w1_##i, W1, tid, i);
#define PHASEA(i) { f16x8 h0c = h0q[i]; DOT8((((i)&1) ? z0b : z0a), h0c, u0_##i); \
                    f16x8 h1c = h1q[i]; DOT8((((i)&1) ? zub : zua), h1c, u1_##i); }
#define PHASEC(i) { f16x8 h0c = h0q[i]; DOT8((((i)&1) ? z1b : z1a), h0c, w1_##i); }

__global__ __launch_bounds__(512, 2) void k_lstm_f3(
    const float* __restrict__ Z0x,
    const float* __restrict__ U0, const float* __restrict__ W1,
    const float* __restrict__ U1, const float* __restrict__ b1,
    float* __restrict__ y)
{
    const int b = blockIdx.x;
    const int tid = threadIdx.x;

    __shared__ _Float16 h0p[HD];
    __shared__ _Float16 h1p[HD];
    __shared__ float zb[G4];
    __shared__ float zu[G4];

    REPEAT16(DECLW)
    REPEAT16(LOADW)

    const float b1c = b1[tid];
    const float* __restrict__ zrow = Z0x + (size_t)b * TT * G4;

    float c0 = 0.f, c1 = 0.f;   // cell states (threads 0..127)
    if (tid < HD) { h0p[tid] = (_Float16)0.f; h1p[tid] = (_Float16)0.f; }
    __syncthreads();

    const f16x8* h0q = (const f16x8*)h0p;   // 16 chunks of 8 halves
    const f16x8* h1q = (const f16x8*)h1p;

    for (int t = 0; t < TT; ++t) {
        // ---- phase A: z0 = Z0x[b,t] + h0@U0 ; zu = h1@U1 ----
        float z0a = 0.f, z0b = 0.f, zua = 0.f, zub = 0.f;
        float zin = zrow[(size_t)t * G4 + tid];
        REPEAT16(PHASEA)
        zb[tid] = (z0a + z0b) + zin;
        zu[tid] = zua + zub;
        __syncthreads();

        // ---- phase B: layer-0 gates -> h0_t ----
        if (tid < HD) {
            float zi = zb[tid], zf = zb[HD + tid], zc = zb[2 * HD + tid], zo = zb[3 * HD + tid];
            float ig = 1.f / (1.f + expf(-zi));
            float fg = 1.f / (1.f + expf(-zf));
            float og = 1.f / (1.f + expf(-zo));
            c0 = fg * c0 + ig * tanhf(zc);
            h0p[tid] = (_Float16)(og * tanhf(c0));
        }
        __syncthreads();

        // ---- phase C: z1 = b1 + zu + h0_t@W1 ----
        float z1a = b1c + zu[tid], z1b = 0.f;
        REPEAT16(PHASEC)
        zb[tid] = z1a + z1b;
        __syncthreads();

        // ---- phase D: layer-1 gates -> h1_t, y ----
        if (tid < HD) {
            float zi = zb[tid], zf = zb[HD + tid], zc = zb[2 * HD + tid], zo = zb[3 * HD + tid];
            float ig = 1.f / (1.f + expf(-zi));
            float fg = 1.f / (1.f + expf(-zf));
            float og = 1.f / (1.f + expf(-zo));
            c1 = fg * c1 + ig * tanhf(zc);
            float hn = og * tanhf(c1);
            h1p[tid] = (_Float16)hn;
            y[(size_t)(b * TT + t) * HD + tid] = hn;
        }
        __syncthreads();
    }
}

// ---------------- Prep: split y into f16 hi/lo, MFMA-fragment-packed ----------------
__global__ __launch_bounds__(256) void k_ysplit(
    const float* __restrict__ y, _Float16* __restrict__ yhi, _Float16* __restrict__ ylo)
{
    const int g = blockIdx.x * 256 + threadIdx.x;
    const int chunk = g >> 6;           // 0..1023
    const int lane = g & 63;
    const int mtile = chunk >> 2;
    const int kstep = chunk & 3;
    const int row = mtile * 16 + (lane & 15);
    const int kb = kstep * 32 + (lane >> 4) * 8;
    _Float16 hi[8], lo[8];
    #pragma unroll
    for (int j = 0; j < 8; ++j) {
        float v = y[(size_t)row * HD + kb + j];
        hi[j] = (_Float16)v;
        lo[j] = (_Float16)(v - (float)hi[j]);
    }
    *(float4*)&yhi[(size_t)chunk * 512 + lane * 8] = *(const float4*)hi;
    *(float4*)&ylo[(size_t)chunk * 512 + lane * 8] = *(const float4*)lo;
}

// ---------------- Kernel C (MFMA): out = y @ Wd + bd via f16 hi/lo split ----------------
__global__ __launch_bounds__(256) void k_dense_mfma(
    const _Float16* __restrict__ yhi, const _Float16* __restrict__ ylo,
    const _Float16* __restrict__ Whi, const _Float16* __restrict__ Wlo,
    const float* __restrict__ bd, float* __restrict__ out)
{
    const int tid = threadIdx.x;
    const int w = tid >> 6;
    const int lane = tid & 63;
    const int mtile = blockIdx.x * 4 + w;
    const int nt0 = blockIdx.y * 20;

    f16x8 Ah[4], Al[4];
    #pragma unroll
    for (int k = 0; k < 4; ++k) {
        Ah[k] = *(const f16x8*)&yhi[(size_t)(mtile * 4 + k) * 512 + lane * 8];
        Al[k] = *(const f16x8*)&ylo[(size_t)(mtile * 4 + k) * 512 + lane * 8];
    }

    const int m0 = mtile * 16;
    const int r0 = (lane >> 4) * 4;          // C/D row group (m89 mapping)

    for (int nt = 0; nt < 20; ++nt) {
        const int ntile = nt0 + nt;
        const size_t cbb = (size_t)ntile * 4 * 512 + lane * 8;
        f16x8 Bh[4], Bl[4];
        #pragma unroll
        for (int k = 0; k < 4; ++k) {
            Bh[k] = *(const f16x8*)&Whi[cbb + k * 512];
            Bl[k] = *(const f16x8*)&Wlo[cbb + k * 512];
        }
        f32x4 acc0 = {0.f, 0.f, 0.f, 0.f};
        f32x4 acc1 = {0.f, 0.f, 0.f, 0.f};
        #pragma unroll
        for (int k = 0; k < 4; ++k) {
            acc0 = __builtin_amdgcn_mfma_f32_16x16x32_f16(Ah[k], Bh[k], acc0, 0, 0, 0);
            acc1 = __builtin_amdgcn_mfma_f32_16x16x32_f16(Ah[k], Bl[k], acc1, 0, 0, 0);
            acc1 = __builtin_amdgcn_mfma_f32_16x16x32_f16(Al[k], Bh[k], acc1, 0, 0, 0);
        }
        const int col = ntile * 16 + (lane & 15);
        const float bias = bd[col];
        #pragma unroll
        for (int reg = 0; reg < 4; ++reg) {
            out[(size_t)(m0 + r0 + reg) * NV + col] = acc0[reg] + acc1[reg] + bias;
        }
    }
}

// ---------------- Kernel C (fallback, fp32 vector) ----------------
__global__ __launch_bounds__(256) void k_dense(
    const float* __restrict__ y, const float* __restrict__ Wd,
    const float* __restrict__ bd, float* __restrict__ out)
{
    __shared__ float ys[64 * HD];
    const int r0 = blockIdx.x * 64;
    const int v0 = blockIdx.y * 128;
    const int tid = threadIdx.x;
    for (int idx = tid; idx < 64 * HD; idx += 256) ys[idx] = y[(size_t)r0 * HD + idx];
    __syncthreads();
    const int tx = tid & 31;
    const int ty = tid >> 5;
    const int v = v0 + tx * 4;
    float4 bd4 = *(const float4*)&bd[v];
    float acc[8][4] = {};
    const float* yrow = &ys[(ty * 8) * HD];
    #pragma unroll 4
    for (int e = 0; e < HD; ++e) {
        float4 wv = *(const float4*)&Wd[(size_t)e * NV + v];
        #pragma unroll
        for (int j = 0; j < 8; ++j) {
            float yv = yrow[j * HD + e];
            acc[j][0] = fmaf(yv, wv.x, acc[j][0]);
            acc[j][1] = fmaf(yv, wv.y, acc[j][1]);
            acc[j][2] = fmaf(yv, wv.z, acc[j][2]);
            acc[j][3] = fmaf(yv, wv.w, acc[j][3]);
        }
    }
    #pragma unroll
    for (int j = 0; j < 8; ++j) {
        int rr = r0 + ty * 8 + j;
        float4 o4;
        o4.x = acc[j][0] + bd4.x;
        o4.y = acc[j][1] + bd4.y;
        o4.z = acc[j][2] + bd4.z;
        o4.w = acc[j][3] + bd4.w;
        *(float4*)&out[(size_t)rr * NV + v] = o4;
    }
}

extern "C" void kernel_launch(void* const* d_in, const int* in_sizes, int n_in,
                              void* d_out, int out_size, void* d_ws, size_t ws_size,
                              hipStream_t stream)
{
    const int*   inputs = (const int*)  d_in[0];
    const float* emb    = (const float*)d_in[1];
    const float* W0     = (const float*)d_in[2];
    const float* U0     = (const float*)d_in[3];
    const float* b0     = (const float*)d_in[4];
    const float* W1     = (const float*)d_in[5];
    const float* U1     = (const float*)d_in[6];
    const float* b1     = (const float*)d_in[7];
    const float* Wd     = (const float*)d_in[8];
    const float* bd     = (const float*)d_in[9];
    float* out = (float*)d_out;

    // ws layout (MFMA path): Z0x 8MB | yy 2MB | Whi 8MB | Wlo 8MB | yhi 1MB | ylo 1MB
    const size_t Z0X_B = (size_t)8 * 1024 * 1024;
    const size_t YY_B  = (size_t)2 * 1024 * 1024;
    const size_t WSP_B = (size_t)8000 * 512 * 2;        // 8,192,000
    const size_t YSP_B = (size_t)1024 * 512 * 2;        // 1,048,576
    const size_t NEED  = Z0X_B + YY_B + 2 * WSP_B + 2 * YSP_B + 4096;

    char* ws = (char*)d_ws;

    if (ws_size >= NEED) {
        float*     Z0x = (float*)ws;
        float*     yy  = (float*)(ws + Z0X_B);
        _Float16*  Whi = (_Float16*)(ws + Z0X_B + YY_B);
        _Float16*  Wlo = (_Float16*)(ws + Z0X_B + YY_B + WSP_B);
        _Float16*  yhi = (_Float16*)(ws + Z0X_B + YY_B + 2 * WSP_B);
        _Float16*  ylo = (_Float16*)(ws + Z0X_B + YY_B + 2 * WSP_B + YSP_B);

        k_prep<<<2512, 256, 0, stream>>>(inputs, emb, W0, b0, Z0x, Wd, Whi, Wlo);
        k_lstm_f3<<<BB, 512, 0, stream>>>(Z0x, U0, W1, U1, b1, yy);
        k_ysplit<<<256, 256, 0, stream>>>(yy, yhi, ylo);
        k_dense_mfma<<<dim3(64, 100), 256, 0, stream>>>(yhi, ylo, Whi, Wlo, bd, out);
    } else {
        // small-ws fallback: Z0x in d_out tail, yy in ws, fp32 dense
        float* yy = (float*)ws;
        size_t out_bytes = (size_t)out_size * sizeof(float);
        float* Z0x = (float*)((char*)d_out + out_bytes - Z0X_B);

        k_prep<<<2512, 256, 0, stream>>>(inputs, emb, W0, b0, Z0x,
                                         Wd, nullptr, nullptr);
        k_lstm_f3<<<BB, 512, 0, stream>>>(Z0x, U0, W1, U1, b1, yy);
        k_dense<<<dim3(64, 250), 256, 0, stream>>>(yy, Wd, bd, out);
    }
}